// Round 9
// baseline (524.327 us; speedup 1.0000x reference)
//
#include <hip/hip_runtime.h>
#include <hip/hip_bf16.h>

#define TSTEPS 127
#define HDIM   128
#define NB     8      // valid batches per block; LDS rows 8..15 DUPLICATE rows 0..7
#define NBROW  16     // MFMA M
#define NBATCH 2048

typedef __attribute__((ext_vector_type(8))) short bfrag;
typedef __attribute__((ext_vector_type(4))) float f32x4;

static __device__ __forceinline__ unsigned short f2bf(float f) {
  union { float f; unsigned u; } v; v.f = f;
  unsigned r = (v.u + 0x7FFFu + ((v.u >> 16) & 1u)) >> 16;  // RNE (cold paths)
  return (unsigned short)r;
}
static __device__ __forceinline__ unsigned short f2bf_fast(float f) {
  unsigned r;
  asm("v_cvt_pk_bf16_f32 %0, %1, 0" : "=v"(r) : "v"(f));
  return (unsigned short)r;
}

// Polynomial gates (r8-verified): FMA-only, no quarter-rate trans ops.
static __device__ __forceinline__ float tanh_p(float x) {
  x = fminf(2.0f, fmaxf(-2.0f, x));
  const float t = x * x;
  float p = fmaf(0.00282f, t, -0.0281139f);
  p = fmaf(p, t, 0.1176519f);
  p = fmaf(p, t, -0.3307639f);
  p = fmaf(p, t, 1.0f);
  return x * p;
}
static __device__ __forceinline__ float sigm_p(float x) {
  x = fminf(4.0f, fmaxf(-4.0f, x));
  const float t = x * x;
  float p = fmaf(1.10156e-5f, t, -4.3928e-4f);
  p = fmaf(p, t, 7.3532e-3f);
  p = fmaf(p, t, -0.08269098f);
  p = fmaf(p, t, 1.0f);
  return fmaf(x * p, 0.25f, 0.5f);
}

// 256 blocks x 1024 threads = 1 block/CU, 16 waves (4/SIMD):
//   waves 0-7  -> LSTM1 on batches [8*bid, 8*bid+8)
//   waves 8-15 -> LSTM2 on the same batches
// Two independent dependency chains per SIMD fill each other's stalls
// (r7's 1024-thr failure was its 2-barrier gate-split, not the wave count).
// M padded to 16 by DUPLICATING batch rows (r5-verified); epilogue = static
// select, 2 (b,u) per lane. Poly gates (r8-verified). One RAW barrier/step.
__global__ __launch_bounds__(1024, 1)
void enc_kernel(const float* __restrict__ X, const float* __restrict__ yprev,
                const float* __restrict__ Wa,
                const float* __restrict__ Wih1, const float* __restrict__ Whh1,
                const float* __restrict__ bih1, const float* __restrict__ bhh1,
                const float* __restrict__ Wih2, const float* __restrict__ Whh2,
                const float* __restrict__ bih2, const float* __restrict__ bhh2,
                float* __restrict__ out)
{
  const int tid  = threadIdx.x;
  const int wv   = tid >> 6;             // 0..15
  const int lane = tid & 63;
  const int l15  = lane & 15;
  const int lg   = lane >> 4;            // k-group 0..3
  const int lstm = wv >> 3;              // wave's LSTM
  const int w8   = wv & 7;               // u-slice within LSTM
  const int btile = blockIdx.x;          // 0..255

  const float* Wih = lstm ? Wih2 : Wih1;
  const float* Whh = lstm ? Whh2 : Whh1;
  const float* bih = lstm ? bih2 : bih1;
  const float* bhh = lstm ? bhh2 : bhh1;
  const int Kin = lstm ? 15 : 16;

  // [lstm][dbuf][...]
  __shared__ __align__(16) unsigned short h_lds[2][2][NBROW * HDIM];   // 16 KB
  __shared__ __align__(16) unsigned short xt_lds[2][2][NBROW * 40];    // 5 KB

  // ---- time-invariant weight B-fragments (wave's own LSTM) ----
  bfrag wb[4][4];
  bfrag wi[4];
  float bias[4];
  #pragma unroll
  for (int gt = 0; gt < 4; ++gt) {
    const int row = (gt * 8 + w8) * 16 + l15;
    const float* wr = Whh + row * HDIM;
    #pragma unroll
    for (int ks = 0; ks < 4; ++ks) {
      const int k0 = ks * 32 + lg * 8;
      bfrag v;
      #pragma unroll
      for (int e = 0; e < 8; ++e) v[e] = (short)f2bf(wr[k0 + e]);
      wb[gt][ks] = v;
    }
    bfrag v;
    #pragma unroll
    for (int e = 0; e < 8; ++e) {
      const int k = lg * 8 + e;
      v[e] = (k < Kin) ? (short)f2bf(Wih[row * Kin + k]) : (short)0;
    }
    wi[gt] = v;
    bias[gt] = bih[row] + bhh[row];
  }

  // ---- attention: tid<256 covers {lstm al} x {8 batches} x {16 features} ----
  float a_bk = 0.0f;
  const int al   = tid >> 7;             // staging thread's LSTM (al != wave lstm ok)
  const int bloc = (tid >> 4) & 7;
  const int kf   = tid & 15;
  const int KinA = al ? 15 : 16;
  const size_t bg = (size_t)btile * NB + bloc;
  if (tid < 256) {
    float s = -1e30f;
    if (kf < KinA) {
      s = 0.0f;
      const float* xrow = X + bg * TSTEPS * 15;
      const float* yrow = yprev + bg * TSTEPS;
      for (int t = 0; t < TSTEPS; ++t) {
        const float wa = Wa[256 + t];
        float feat;
        if (al == 0) feat = (kf < 15) ? xrow[t * 15 + kf] : yrow[t];
        else         feat = xrow[t * 15 + kf] * yrow[t];
        s += feat * wa;
      }
    }
    float mx = s;
    #pragma unroll
    for (int m = 1; m < 16; m <<= 1) mx = fmaxf(mx, __shfl_xor(mx, m));
    const float e = __expf(s - mx);
    float sum = e;
    #pragma unroll
    for (int m = 1; m < 16; m <<= 1) sum += __shfl_xor(sum, m);
    a_bk = e / sum;
  }

  // ---- zero LDS (h(-1)=0; xt K-pad cols 16..31), barrier before staging ----
  for (int i = tid; i < 2 * 2 * NBROW * HDIM; i += 1024) ((unsigned short*)h_lds)[i] = 0;
  for (int i = tid; i < 2 * 2 * NBROW * 40;   i += 1024) ((unsigned short*)xt_lds)[i] = 0;
  __syncthreads();

  // ---- epilogue lane mapping (r5-verified): 2 valid rows, static regs ----
  const int row0 = (lg & 1) * 4 + (lg >> 1) * 2;   // {0,4,2,6}
  const int row1 = row0 + 1;                       // {1,5,3,7}
  const int u = w8 * 16 + l15;

  const size_t XT_TOTAL = (size_t)NBATCH * TSTEPS * 16;
  float* pH0 = out + XT_TOTAL + ((size_t)btile * NB + row0) * (TSTEPS * 256) + (size_t)lstm * 128 + u;
  float* pH1 = out + XT_TOTAL + ((size_t)btile * NB + row1) * (TSTEPS * 256) + (size_t)lstm * 128 + u;
  float* pXT = out + bg * (TSTEPS * 16) + kf;
  const float* pX = X + bg * (TSTEPS * 15) + kf;
  const float* pY = yprev + bg * TSTEPS;

  // ---- prologue: stage xt(0) (duplicated rows), prefetch for s=1 ----
  float xv = 0.f, yv = 0.f;
  if (tid < 256) {
    yv = pY[0];
    if (kf < 15) xv = pX[0];
    float feat;
    if (al == 0) feat = (kf < 15) ? xv : yv;
    else         feat = (kf < 15) ? xv * yv : 0.0f;
    const float xt = a_bk * feat;
    const unsigned short xtb = f2bf(xt);
    xt_lds[al][0][bloc * 40 + kf] = xtb;
    xt_lds[al][0][(bloc + 8) * 40 + kf] = xtb;
    if (al == 0) pXT[0] = xt;
    yv = pY[1];
    if (kf < 15) xv = pX[15];
  }
  __syncthreads();

  float cr0 = 0.f, cr1 = 0.f;            // c for (row0,u), (row1,u)

  #pragma unroll 2
  for (int t = 0; t < TSTEPS; ++t) {
    // ---- A-fragments: h(t-1) from buf (t+1)&1, xt(t) from buf t&1 ----
    bfrag ah[4], ax;
    #pragma unroll
    for (int ks = 0; ks < 4; ++ks) {
      const int idx = (l15 * HDIM + ks * 32 + lg * 8) ^ (l15 << 3);
      ah[ks] = *(const bfrag*)&h_lds[lstm][(t + 1) & 1][idx];
    }
    ax = *(const bfrag*)&xt_lds[lstm][t & 1][l15 * 40 + lg * 8];

    // ---- 20 MFMAs/wave (M=16, duplicated rows) ----
    f32x4 acc[4];
    #pragma unroll
    for (int gt = 0; gt < 4; ++gt) {
      f32x4 a = {bias[gt], bias[gt], bias[gt], bias[gt]};
      #pragma unroll
      for (int ks = 0; ks < 4; ++ks)
        a = __builtin_amdgcn_mfma_f32_16x16x32_bf16(ah[ks], wb[gt][ks], a, 0, 0, 0);
      a = __builtin_amdgcn_mfma_f32_16x16x32_bf16(ax, wi[gt], a, 0, 0, 0);
      acc[gt] = a;
    }

    // ---- static select of this lane's 2 valid rows ----
    float g0[4], g1[4];
    #pragma unroll
    for (int gt = 0; gt < 4; ++gt) {
      g0[gt] = (lg < 2) ? acc[gt][0] : acc[gt][2];
      g1[gt] = (lg < 2) ? acc[gt][1] : acc[gt][3];
    }

    // ---- gates (poly) -> c,h; duplicated LDS h writes; global h stores ----
    {
      const float ig = sigm_p(g0[0]), fg = sigm_p(g0[1]);
      const float gg = tanh_p(g0[2]), og = sigm_p(g0[3]);
      const float c = fg * cr0 + ig * gg;  cr0 = c;
      const float h = og * tanh_p(c);
      const unsigned short hb = f2bf_fast(h);
      h_lds[lstm][t & 1][(row0 * HDIM + u) ^ (row0 << 3)] = hb;
      h_lds[lstm][t & 1][((row0 + 8) * HDIM + u) ^ ((row0 + 8) << 3)] = hb;
      *pH0 = h;  pH0 += 256;
    }
    {
      const float ig = sigm_p(g1[0]), fg = sigm_p(g1[1]);
      const float gg = tanh_p(g1[2]), og = sigm_p(g1[3]);
      const float c = fg * cr1 + ig * gg;  cr1 = c;
      const float h = og * tanh_p(c);
      const unsigned short hb = f2bf_fast(h);
      h_lds[lstm][t & 1][(row1 * HDIM + u) ^ (row1 << 3)] = hb;
      h_lds[lstm][t & 1][((row1 + 8) * HDIM + u) ^ ((row1 + 8) << 3)] = hb;
      *pH1 = h;  pH1 += 256;
    }

    // ---- stage xt(t+1) (duplicated), prefetch s=t+2 ----
    if (tid < 256 && t < TSTEPS - 1) {
      float feat;
      if (al == 0) feat = (kf < 15) ? xv : yv;
      else         feat = (kf < 15) ? xv * yv : 0.0f;
      const float xt = a_bk * feat;
      const unsigned short xtb = f2bf_fast(xt);
      xt_lds[al][(t + 1) & 1][bloc * 40 + kf] = xtb;
      xt_lds[al][(t + 1) & 1][(bloc + 8) * 40 + kf] = xtb;
      if (al == 0) pXT[(size_t)(t + 1) * 16] = xt;
      if (t < TSTEPS - 2) {
        yv = pY[t + 2];
        if (kf < 15) xv = pX[(size_t)(t + 2) * 15];
      }
    }

    // ---- RAW barrier: LDS-only ordering; vmcnt free-running ----
    asm volatile("s_waitcnt lgkmcnt(0)" ::: "memory");
    __builtin_amdgcn_s_barrier();
    __builtin_amdgcn_sched_barrier(0);
  }
}

extern "C" void kernel_launch(void* const* d_in, const int* in_sizes, int n_in,
                              void* d_out, int out_size, void* d_ws, size_t ws_size,
                              hipStream_t stream) {
  const float* X    = (const float*)d_in[0];
  const float* yp   = (const float*)d_in[1];
  const float* Wa   = (const float*)d_in[2];
  // d_in[3] = ba: shift-invariant under softmax, unused
  const float* Wih1 = (const float*)d_in[4];
  const float* Whh1 = (const float*)d_in[5];
  const float* bih1 = (const float*)d_in[6];
  const float* bhh1 = (const float*)d_in[7];
  const float* Wih2 = (const float*)d_in[8];
  const float* Whh2 = (const float*)d_in[9];
  const float* bih2 = (const float*)d_in[10];
  const float* bhh2 = (const float*)d_in[11];
  float* out = (float*)d_out;

  enc_kernel<<<dim3(256), dim3(1024), 0, stream>>>(
      X, yp, Wa, Wih1, Whh1, bih1, bhh1, Wih2, Whh2, bih2, bhh2, out);
}

// Round 10
// 521.821 us; speedup vs baseline: 1.0048x; 1.0048x over previous
//
#include <hip/hip_runtime.h>
#include <hip/hip_bf16.h>

#define TSTEPS 127
#define HDIM   128
#define NB     8      // valid batches per block; LDS rows 8..15 DUPLICATE rows 0..7
#define NBROW  16     // MFMA M
#define NBATCH 2048

typedef __attribute__((ext_vector_type(8))) short bfrag;
typedef __attribute__((ext_vector_type(4))) float f32x4;

static __device__ __forceinline__ unsigned short f2bf(float f) {
  union { float f; unsigned u; } v; v.f = f;
  unsigned r = (v.u + 0x7FFFu + ((v.u >> 16) & 1u)) >> 16;  // RNE (cold paths)
  return (unsigned short)r;
}
static __device__ __forceinline__ unsigned short f2bf_fast(float f) {
  unsigned r;
  asm("v_cvt_pk_bf16_f32 %0, %1, 0" : "=v"(r) : "v"(f));
  return (unsigned short)r;
}

// Polynomial gates (r8-verified): FMA-only, no quarter-rate trans ops.
static __device__ __forceinline__ float tanh_p(float x) {
  x = fminf(2.0f, fmaxf(-2.0f, x));
  const float t = x * x;
  float p = fmaf(0.00282f, t, -0.0281139f);
  p = fmaf(p, t, 0.1176519f);
  p = fmaf(p, t, -0.3307639f);
  p = fmaf(p, t, 1.0f);
  return x * p;
}
static __device__ __forceinline__ float sigm_p(float x) {
  x = fminf(4.0f, fmaxf(-4.0f, x));
  const float t = x * x;
  float p = fmaf(1.10156e-5f, t, -4.3928e-4f);
  p = fmaf(p, t, 7.3532e-3f);
  p = fmaf(p, t, -0.08269098f);
  p = fmaf(p, t, 1.0f);
  return fmaf(x * p, 0.25f, 0.5f);
}

// 256 blocks x 1024 threads = 1 block/CU, 16 waves (4/SIMD):
//   waves 0-7  -> LSTM1 on batches [8*bid, 8*bid+8)
//   waves 8-15 -> LSTM2 on the same batches
// Per SIMD: 2 LSTM1-waves + 2 LSTM2-waves = 2 independent dependency chains
// filling each other's stalls between the shared per-step barriers.
//
// REGISTER-BUDGET NOTE (r5/r9 post-mortems): the backend's occupancy
// heuristic capped VGPR at 64 (8 waves/EU target) for this 1024-thr kernel
// despite launch_bounds(1024,1), spilling ~40 regs -> +500 MB scratch HBM
// traffic. amdgpu_waves_per_eu(4,4) pins exactly 4 waves/EU -> 128-VGPR
// budget; kernel needs ~104.
__global__ __launch_bounds__(1024, 1)
__attribute__((amdgpu_waves_per_eu(4, 4)))
void enc_kernel(const float* __restrict__ X, const float* __restrict__ yprev,
                const float* __restrict__ Wa,
                const float* __restrict__ Wih1, const float* __restrict__ Whh1,
                const float* __restrict__ bih1, const float* __restrict__ bhh1,
                const float* __restrict__ Wih2, const float* __restrict__ Whh2,
                const float* __restrict__ bih2, const float* __restrict__ bhh2,
                float* __restrict__ out)
{
  const int tid  = threadIdx.x;
  const int wv   = tid >> 6;             // 0..15
  const int lane = tid & 63;
  const int l15  = lane & 15;
  const int lg   = lane >> 4;            // k-group 0..3
  const int lstm = wv >> 3;              // wave's LSTM
  const int w8   = wv & 7;               // u-slice within LSTM
  const int btile = blockIdx.x;          // 0..255

  const float* Wih = lstm ? Wih2 : Wih1;
  const float* Whh = lstm ? Whh2 : Whh1;
  const float* bih = lstm ? bih2 : bih1;
  const float* bhh = lstm ? bhh2 : bhh1;
  const int Kin = lstm ? 15 : 16;

  // [lstm][dbuf][...]
  __shared__ __align__(16) unsigned short h_lds[2][2][NBROW * HDIM];   // 16 KB
  __shared__ __align__(16) unsigned short xt_lds[2][2][NBROW * 40];    // 5 KB

  // ---- time-invariant weight B-fragments (wave's own LSTM) ----
  bfrag wb[4][4];
  bfrag wi[4];
  float bias[4];
  #pragma unroll
  for (int gt = 0; gt < 4; ++gt) {
    const int row = (gt * 8 + w8) * 16 + l15;
    const float* wr = Whh + row * HDIM;
    #pragma unroll
    for (int ks = 0; ks < 4; ++ks) {
      const int k0 = ks * 32 + lg * 8;
      bfrag v;
      #pragma unroll
      for (int e = 0; e < 8; ++e) v[e] = (short)f2bf(wr[k0 + e]);
      wb[gt][ks] = v;
    }
    bfrag v;
    #pragma unroll
    for (int e = 0; e < 8; ++e) {
      const int k = lg * 8 + e;
      v[e] = (k < Kin) ? (short)f2bf(Wih[row * Kin + k]) : (short)0;
    }
    wi[gt] = v;
    bias[gt] = bih[row] + bhh[row];
  }

  // ---- attention: tid<256 covers {lstm al} x {8 batches} x {16 features} ----
  float a_bk = 0.0f;
  const int al   = tid >> 7;             // staging thread's LSTM (al != wave lstm ok)
  const int bloc = (tid >> 4) & 7;
  const int kf   = tid & 15;
  const int KinA = al ? 15 : 16;
  const size_t bg = (size_t)btile * NB + bloc;
  if (tid < 256) {
    float s = -1e30f;
    if (kf < KinA) {
      s = 0.0f;
      const float* xrow = X + bg * TSTEPS * 15;
      const float* yrow = yprev + bg * TSTEPS;
      for (int t = 0; t < TSTEPS; ++t) {
        const float wa = Wa[256 + t];
        float feat;
        if (al == 0) feat = (kf < 15) ? xrow[t * 15 + kf] : yrow[t];
        else         feat = xrow[t * 15 + kf] * yrow[t];
        s += feat * wa;
      }
    }
    float mx = s;
    #pragma unroll
    for (int m = 1; m < 16; m <<= 1) mx = fmaxf(mx, __shfl_xor(mx, m));
    const float e = __expf(s - mx);
    float sum = e;
    #pragma unroll
    for (int m = 1; m < 16; m <<= 1) sum += __shfl_xor(sum, m);
    a_bk = e / sum;
  }

  // ---- zero LDS (h(-1)=0; xt K-pad cols 16..31), barrier before staging ----
  for (int i = tid; i < 2 * 2 * NBROW * HDIM; i += 1024) ((unsigned short*)h_lds)[i] = 0;
  for (int i = tid; i < 2 * 2 * NBROW * 40;   i += 1024) ((unsigned short*)xt_lds)[i] = 0;
  __syncthreads();

  // ---- epilogue lane mapping (r5-verified): 2 valid rows, static regs ----
  const int row0 = (lg & 1) * 4 + (lg >> 1) * 2;   // {0,4,2,6}
  const int row1 = row0 + 1;                       // {1,5,3,7}
  const int u = w8 * 16 + l15;

  const size_t XT_TOTAL = (size_t)NBATCH * TSTEPS * 16;
  float* pH0 = out + XT_TOTAL + ((size_t)btile * NB + row0) * (TSTEPS * 256) + (size_t)lstm * 128 + u;
  float* pH1 = out + XT_TOTAL + ((size_t)btile * NB + row1) * (TSTEPS * 256) + (size_t)lstm * 128 + u;
  float* pXT = out + bg * (TSTEPS * 16) + kf;
  const float* pX = X + bg * (TSTEPS * 15) + kf;
  const float* pY = yprev + bg * TSTEPS;

  // ---- prologue: stage xt(0) (duplicated rows), prefetch for s=1 ----
  float xv = 0.f, yv = 0.f;
  if (tid < 256) {
    yv = pY[0];
    if (kf < 15) xv = pX[0];
    float feat;
    if (al == 0) feat = (kf < 15) ? xv : yv;
    else         feat = (kf < 15) ? xv * yv : 0.0f;
    const float xt = a_bk * feat;
    const unsigned short xtb = f2bf(xt);
    xt_lds[al][0][bloc * 40 + kf] = xtb;
    xt_lds[al][0][(bloc + 8) * 40 + kf] = xtb;
    if (al == 0) pXT[0] = xt;
    yv = pY[1];
    if (kf < 15) xv = pX[15];
  }
  __syncthreads();

  float cr0 = 0.f, cr1 = 0.f;            // c for (row0,u), (row1,u)

  #pragma unroll 2
  for (int t = 0; t < TSTEPS; ++t) {
    // ---- A-fragments: h(t-1) from buf (t+1)&1, xt(t) from buf t&1 ----
    bfrag ah[4], ax;
    #pragma unroll
    for (int ks = 0; ks < 4; ++ks) {
      const int idx = (l15 * HDIM + ks * 32 + lg * 8) ^ (l15 << 3);
      ah[ks] = *(const bfrag*)&h_lds[lstm][(t + 1) & 1][idx];
    }
    ax = *(const bfrag*)&xt_lds[lstm][t & 1][l15 * 40 + lg * 8];

    // ---- 20 MFMAs/wave (M=16, duplicated rows) ----
    f32x4 acc[4];
    #pragma unroll
    for (int gt = 0; gt < 4; ++gt) {
      f32x4 a = {bias[gt], bias[gt], bias[gt], bias[gt]};
      #pragma unroll
      for (int ks = 0; ks < 4; ++ks)
        a = __builtin_amdgcn_mfma_f32_16x16x32_bf16(ah[ks], wb[gt][ks], a, 0, 0, 0);
      a = __builtin_amdgcn_mfma_f32_16x16x32_bf16(ax, wi[gt], a, 0, 0, 0);
      acc[gt] = a;
    }

    // ---- static select of this lane's 2 valid rows ----
    float g0[4], g1[4];
    #pragma unroll
    for (int gt = 0; gt < 4; ++gt) {
      g0[gt] = (lg < 2) ? acc[gt][0] : acc[gt][2];
      g1[gt] = (lg < 2) ? acc[gt][1] : acc[gt][3];
    }

    // ---- gates (poly) -> c,h; duplicated LDS h writes; global h stores ----
    {
      const float ig = sigm_p(g0[0]), fg = sigm_p(g0[1]);
      const float gg = tanh_p(g0[2]), og = sigm_p(g0[3]);
      const float c = fg * cr0 + ig * gg;  cr0 = c;
      const float h = og * tanh_p(c);
      const unsigned short hb = f2bf_fast(h);
      h_lds[lstm][t & 1][(row0 * HDIM + u) ^ (row0 << 3)] = hb;
      h_lds[lstm][t & 1][((row0 + 8) * HDIM + u) ^ ((row0 + 8) << 3)] = hb;
      *pH0 = h;  pH0 += 256;
    }
    {
      const float ig = sigm_p(g1[0]), fg = sigm_p(g1[1]);
      const float gg = tanh_p(g1[2]), og = sigm_p(g1[3]);
      const float c = fg * cr1 + ig * gg;  cr1 = c;
      const float h = og * tanh_p(c);
      const unsigned short hb = f2bf_fast(h);
      h_lds[lstm][t & 1][(row1 * HDIM + u) ^ (row1 << 3)] = hb;
      h_lds[lstm][t & 1][((row1 + 8) * HDIM + u) ^ ((row1 + 8) << 3)] = hb;
      *pH1 = h;  pH1 += 256;
    }

    // ---- stage xt(t+1) (duplicated), prefetch s=t+2 ----
    if (tid < 256 && t < TSTEPS - 1) {
      float feat;
      if (al == 0) feat = (kf < 15) ? xv : yv;
      else         feat = (kf < 15) ? xv * yv : 0.0f;
      const float xt = a_bk * feat;
      const unsigned short xtb = f2bf_fast(xt);
      xt_lds[al][(t + 1) & 1][bloc * 40 + kf] = xtb;
      xt_lds[al][(t + 1) & 1][(bloc + 8) * 40 + kf] = xtb;
      if (al == 0) pXT[(size_t)(t + 1) * 16] = xt;
      if (t < TSTEPS - 2) {
        yv = pY[t + 2];
        if (kf < 15) xv = pX[(size_t)(t + 2) * 15];
      }
    }

    // ---- RAW barrier: LDS-only ordering; vmcnt free-running ----
    asm volatile("s_waitcnt lgkmcnt(0)" ::: "memory");
    __builtin_amdgcn_s_barrier();
    __builtin_amdgcn_sched_barrier(0);
  }
}

extern "C" void kernel_launch(void* const* d_in, const int* in_sizes, int n_in,
                              void* d_out, int out_size, void* d_ws, size_t ws_size,
                              hipStream_t stream) {
  const float* X    = (const float*)d_in[0];
  const float* yp   = (const float*)d_in[1];
  const float* Wa   = (const float*)d_in[2];
  // d_in[3] = ba: shift-invariant under softmax, unused
  const float* Wih1 = (const float*)d_in[4];
  const float* Whh1 = (const float*)d_in[5];
  const float* bih1 = (const float*)d_in[6];
  const float* bhh1 = (const float*)d_in[7];
  const float* Wih2 = (const float*)d_in[8];
  const float* Whh2 = (const float*)d_in[9];
  const float* bih2 = (const float*)d_in[10];
  const float* bhh2 = (const float*)d_in[11];
  float* out = (float*)d_out;

  enc_kernel<<<dim3(256), dim3(1024), 0, stream>>>(
      X, yp, Wa, Wih1, Whh1, bih1, bhh1, Wih2, Whh2, bih2, bhh2, out);
}

// Round 11
// 216.799 us; speedup vs baseline: 2.4185x; 2.4069x over previous
//
#include <hip/hip_runtime.h>
#include <hip/hip_bf16.h>

#define TSTEPS 127
#define HDIM   128
#define NBATCH 2048

typedef __attribute__((ext_vector_type(8))) short bfrag;
typedef __attribute__((ext_vector_type(4))) float f32x4;

static __device__ __forceinline__ unsigned short f2bf(float f) {
  union { float f; unsigned u; } v; v.f = f;
  unsigned r = (v.u + 0x7FFFu + ((v.u >> 16) & 1u)) >> 16;  // RNE (cold paths)
  return (unsigned short)r;
}
static __device__ __forceinline__ unsigned short f2bf_fast(float f) {
  unsigned r;
  asm("v_cvt_pk_bf16_f32 %0, %1, 0" : "=v"(r) : "v"(f));
  return (unsigned short)r;
}

// Polynomial gates (r8-verified): FMA-only, no quarter-rate trans ops.
static __device__ __forceinline__ float tanh_p(float x) {
  x = fminf(2.0f, fmaxf(-2.0f, x));
  const float t = x * x;
  float p = fmaf(0.00282f, t, -0.0281139f);
  p = fmaf(p, t, 0.1176519f);
  p = fmaf(p, t, -0.3307639f);
  p = fmaf(p, t, 1.0f);
  return x * p;
}
static __device__ __forceinline__ float sigm_p(float x) {
  x = fminf(4.0f, fmaxf(-4.0f, x));
  const float t = x * x;
  float p = fmaf(1.10156e-5f, t, -4.3928e-4f);
  p = fmaf(p, t, 7.3532e-3f);
  p = fmaf(p, t, -0.08269098f);
  p = fmaf(p, t, 1.0f);
  return fmaf(x * p, 0.25f, 0.5f);
}

#define BARRIER() do {                                         \
    asm volatile("s_waitcnt lgkmcnt(0)" ::: "memory");         \
    __builtin_amdgcn_s_barrier();                              \
    __builtin_amdgcn_sched_barrier(0);                         \
  } while (0)

// 256 blocks x 512 thr (r8 grid; proven full-machine single-pass).
// NEW: two-set software pipeline. Block's 16 batches split into sets
// A (0-7) / B (8-15), phase-shifted by half a step. Per barrier interval:
//   MFMA(set X, step t)  +  epilogue(set Y, prev step)  +  stage(xt for Y)
// The epilogue VALU of one set fills the ds_read/MFMA chain latency of the
// other (independent data). Per-set M=16 via DUPLICATED rows (r5/r9-verified)
// -> 2-(b,u)/lane epilogue (r6's lever). 254 barriers instead of 127.
// acc of each set lives across one barrier (+32 VGPR, ~170 total):
// __launch_bounds__(512,1) -> cap 256 under either 2nd-arg semantics
// (r5/r9/r10 post-mortems: (512,4)/(1024,*) cap at 64 and spill).
__global__ __launch_bounds__(512, 1)
void enc_kernel(const float* __restrict__ X, const float* __restrict__ yprev,
                const float* __restrict__ Wa,
                const float* __restrict__ Wih1, const float* __restrict__ Whh1,
                const float* __restrict__ bih1, const float* __restrict__ bhh1,
                const float* __restrict__ Wih2, const float* __restrict__ Whh2,
                const float* __restrict__ bih2, const float* __restrict__ bhh2,
                float* __restrict__ out)
{
  const int tid  = threadIdx.x;
  const int wv   = tid >> 6;
  const int lane = tid & 63;
  const int l15  = lane & 15;
  const int lg   = lane >> 4;            // k-group 0..3
  const int lstm  = blockIdx.x >> 7;
  const int btile = blockIdx.x & 127;

  const float* Wih = lstm ? Wih2 : Wih1;
  const float* Whh = lstm ? Whh2 : Whh1;
  const float* bih = lstm ? bih2 : bih1;
  const float* bhh = lstm ? bhh2 : bhh1;
  const int Kin = lstm ? 15 : 16;

  // Single-buffered per set (pipeline phases provide the WAR/RAW separation).
  __shared__ __align__(16) unsigned short hA[16 * HDIM], hB[16 * HDIM];   // 8 KB
  __shared__ __align__(16) unsigned short xtA[16 * 40], xtB[16 * 40];     // 2.5 KB

  // ---- time-invariant weight B-fragments (shared by both sets) ----
  bfrag wb[4][4];
  bfrag wi[4];
  float bias[4];
  #pragma unroll
  for (int gt = 0; gt < 4; ++gt) {
    const int row = (gt * 8 + wv) * 16 + l15;
    const float* wr = Whh + row * HDIM;
    #pragma unroll
    for (int ks = 0; ks < 4; ++ks) {
      const int k0 = ks * 32 + lg * 8;
      bfrag v;
      #pragma unroll
      for (int e = 0; e < 8; ++e) v[e] = (short)f2bf(wr[k0 + e]);
      wb[gt][ks] = v;
    }
    bfrag v;
    #pragma unroll
    for (int e = 0; e < 8; ++e) {
      const int k = lg * 8 + e;
      v[e] = (k < Kin) ? (short)f2bf(Wih[row * Kin + k]) : (short)0;
    }
    wi[gt] = v;
    bias[gt] = bih[row] + bhh[row];
  }

  // ---- attention (r8-verified): h/c terms cancel; time-invariant ----
  float a_bk = 0.0f;
  const int bloc = (tid >> 4) & 15;      // batch 0..15 (set = bloc>>3)
  const int kf   = tid & 15;
  const int sset = bloc >> 3;
  const size_t bg = (size_t)btile * 16 + bloc;
  if (tid < 256) {
    float s = -1e30f;
    if (kf < Kin) {
      s = 0.0f;
      const float* xrow = X + bg * TSTEPS * 15;
      const float* yrow = yprev + bg * TSTEPS;
      for (int t = 0; t < TSTEPS; ++t) {
        const float wa = Wa[256 + t];
        float feat;
        if (lstm == 0) feat = (kf < 15) ? xrow[t * 15 + kf] : yrow[t];
        else           feat = xrow[t * 15 + kf] * yrow[t];
        s += feat * wa;
      }
    }
    float mx = s;
    #pragma unroll
    for (int m = 1; m < 16; m <<= 1) mx = fmaxf(mx, __shfl_xor(mx, m));
    const float e = __expf(s - mx);
    float sum = e;
    #pragma unroll
    for (int m = 1; m < 16; m <<= 1) sum += __shfl_xor(sum, m);
    a_bk = e / sum;
  }

  // ---- zero LDS (h(-1)=0; xt K-pad cols 16..31) ----
  for (int i = tid; i < 16 * HDIM; i += 512) { hA[i] = 0; hB[i] = 0; }
  for (int i = tid; i < 16 * 40;   i += 512) { xtA[i] = 0; xtB[i] = 0; }
  __syncthreads();

  // ---- epilogue lane mapping (r5/r9-verified): 2 valid rows, static regs ----
  const int row0 = (lg & 1) * 4 + (lg >> 1) * 2;   // {0,4,2,6}
  const int row1 = row0 + 1;                       // {1,5,3,7}
  const int u = wv * 16 + l15;

  const size_t XT_TOTAL = (size_t)NBATCH * TSTEPS * 16;
  float* pHA0 = out + XT_TOTAL + ((size_t)btile * 16 + 0 + row0) * (TSTEPS * 256) + (size_t)lstm * 128 + u;
  float* pHA1 = out + XT_TOTAL + ((size_t)btile * 16 + 0 + row1) * (TSTEPS * 256) + (size_t)lstm * 128 + u;
  float* pHB0 = out + XT_TOTAL + ((size_t)btile * 16 + 8 + row0) * (TSTEPS * 256) + (size_t)lstm * 128 + u;
  float* pHB1 = out + XT_TOTAL + ((size_t)btile * 16 + 8 + row1) * (TSTEPS * 256) + (size_t)lstm * 128 + u;
  float* pXTc = out + bg * (TSTEPS * 16) + kf;
  const float* pXn = X + bg * (TSTEPS * 15) + kf;   // next X to load
  const float* pYn = yprev + bg * TSTEPS;           // next y to load
  float xv = 0.f, yv = 0.f;

  // initial input loads (t=0) for all staging threads
  if (tid < 256) {
    yv = pYn[0];  pYn += 1;
    if (kf < 15) xv = pXn[0];
    pXn += 15;
  }

  // stage xt(ts) for set setS; consume (xv,yv), prefetch ts+1
  auto STAGE = [&](int setS, int ts) {
    if (tid < 256 && sset == setS) {
      float feat;
      if (lstm == 0) feat = (kf < 15) ? xv : yv;
      else           feat = (kf < 15) ? xv * yv : 0.0f;
      const float xt = a_bk * feat;
      const unsigned short xtb = f2bf_fast(xt);
      unsigned short* xb = setS ? xtB : xtA;
      const int bl = bloc & 7;
      xb[bl * 40 + kf] = xtb;
      xb[(bl + 8) * 40 + kf] = xtb;
      if (lstm == 0) { *pXTc = xt; pXTc += 16; }
      if (ts < TSTEPS - 1) {
        yv = *pYn;  pYn += 1;
        if (kf < 15) xv = *pXn;
        pXn += 15;
      }
    }
  };

  auto MFMA = [&](const unsigned short* hbuf, const unsigned short* xbuf, f32x4* acc) {
    bfrag ah[4], ax;
    #pragma unroll
    for (int ks = 0; ks < 4; ++ks) {
      const int idx = (l15 * HDIM + ks * 32 + lg * 8) ^ (l15 << 3);
      ah[ks] = *(const bfrag*)&hbuf[idx];
    }
    ax = *(const bfrag*)&xbuf[l15 * 40 + lg * 8];
    #pragma unroll
    for (int gt = 0; gt < 4; ++gt) {
      f32x4 a = {bias[gt], bias[gt], bias[gt], bias[gt]};
      #pragma unroll
      for (int ks = 0; ks < 4; ++ks)
        a = __builtin_amdgcn_mfma_f32_16x16x32_bf16(ah[ks], wb[gt][ks], a, 0, 0, 0);
      a = __builtin_amdgcn_mfma_f32_16x16x32_bf16(ax, wi[gt], a, 0, 0, 0);
      acc[gt] = a;
    }
  };

  auto EPI = [&](const f32x4* acc, unsigned short* hbuf,
                 float*& p0, float*& p1, float& c0, float& c1) {
    float g0[4], g1[4];
    #pragma unroll
    for (int gt = 0; gt < 4; ++gt) {
      g0[gt] = (lg < 2) ? acc[gt][0] : acc[gt][2];
      g1[gt] = (lg < 2) ? acc[gt][1] : acc[gt][3];
    }
    {
      const float ig = sigm_p(g0[0]), fg = sigm_p(g0[1]);
      const float gg = tanh_p(g0[2]), og = sigm_p(g0[3]);
      const float c = fg * c0 + ig * gg;  c0 = c;
      const float h = og * tanh_p(c);
      const unsigned short hb = f2bf_fast(h);
      hbuf[(row0 * HDIM + u) ^ (row0 << 3)] = hb;
      hbuf[((row0 + 8) * HDIM + u) ^ ((row0 + 8) << 3)] = hb;
      *p0 = h;  p0 += 256;
    }
    {
      const float ig = sigm_p(g1[0]), fg = sigm_p(g1[1]);
      const float gg = tanh_p(g1[2]), og = sigm_p(g1[3]);
      const float c = fg * c1 + ig * gg;  c1 = c;
      const float h = og * tanh_p(c);
      const unsigned short hb = f2bf_fast(h);
      hbuf[(row1 * HDIM + u) ^ (row1 << 3)] = hb;
      hbuf[((row1 + 8) * HDIM + u) ^ ((row1 + 8) << 3)] = hb;
      *p1 = h;  p1 += 256;
    }
  };

  // ---- prologue: stage xtA(0); barrier; then pipeline ----
  STAGE(0, 0);
  __syncthreads();

  f32x4 accA[4], accB[4];
  float crA0 = 0.f, crA1 = 0.f, crB0 = 0.f, crB1 = 0.f;

  MFMA(hA, xtA, accA);     // A step 0
  STAGE(1, 0);             // xtB(0)
  BARRIER();

  for (int t = 0; t < TSTEPS - 1; ++t) {
    // interval: B-step t MFMA  ||  A-step t epilogue  ||  stage xtA(t+1)
    MFMA(hB, xtB, accB);
    EPI(accA, hA, pHA0, pHA1, crA0, crA1);
    STAGE(0, t + 1);
    BARRIER();
    // interval: A-step t+1 MFMA  ||  B-step t epilogue  ||  stage xtB(t+1)
    MFMA(hA, xtA, accA);
    EPI(accB, hB, pHB0, pHB1, crB0, crB1);
    STAGE(1, t + 1);
    BARRIER();
  }
  // tail: B step 126 MFMA, then both epilogues (register-dep only)
  MFMA(hB, xtB, accB);
  EPI(accA, hA, pHA0, pHA1, crA0, crA1);
  EPI(accB, hB, pHB0, pHB1, crB0, crB1);
}

extern "C" void kernel_launch(void* const* d_in, const int* in_sizes, int n_in,
                              void* d_out, int out_size, void* d_ws, size_t ws_size,
                              hipStream_t stream) {
  const float* X    = (const float*)d_in[0];
  const float* yp   = (const float*)d_in[1];
  const float* Wa   = (const float*)d_in[2];
  // d_in[3] = ba: shift-invariant under softmax, unused
  const float* Wih1 = (const float*)d_in[4];
  const float* Whh1 = (const float*)d_in[5];
  const float* bih1 = (const float*)d_in[6];
  const float* bhh1 = (const float*)d_in[7];
  const float* Wih2 = (const float*)d_in[8];
  const float* Whh2 = (const float*)d_in[9];
  const float* bih2 = (const float*)d_in[10];
  const float* bhh2 = (const float*)d_in[11];
  float* out = (float*)d_out;

  enc_kernel<<<dim3(256), dim3(512), 0, stream>>>(
      X, yp, Wa, Wih1, Whh1, bih1, bhh1, Wih2, Whh2, bih2, bhh2, out);
}

// Round 12
// 165.053 us; speedup vs baseline: 3.1767x; 1.3135x over previous
//
#include <hip/hip_runtime.h>
#include <hip/hip_bf16.h>

#define TSTEPS 127
#define HDIM   128
#define NB     16
#define NBATCH 2048

typedef __attribute__((ext_vector_type(8))) short bfrag;
typedef __attribute__((ext_vector_type(4))) float f32x4;
typedef __attribute__((ext_vector_type(2))) float f32x2;

static __device__ __forceinline__ unsigned short f2bf(float f) {
  union { float f; unsigned u; } v; v.f = f;
  unsigned r = (v.u + 0x7FFFu + ((v.u >> 16) & 1u)) >> 16;  // RNE (cold paths)
  return (unsigned short)r;
}
static __device__ __forceinline__ unsigned short f2bf_fast(float f) {
  unsigned r;
  asm("v_cvt_pk_bf16_f32 %0, %1, 0" : "=v"(r) : "v"(f));
  return (unsigned short)r;
}

// Packed fp32 math (VOP3P): 2 FMAs per instruction, IEEE f32 precision.
static __device__ __forceinline__ f32x2 pkfma(f32x2 a, f32x2 b, f32x2 c) {
  f32x2 d;
  asm("v_pk_fma_f32 %0, %1, %2, %3" : "=v"(d) : "v"(a), "v"(b), "v"(c));
  return d;
}
static __device__ __forceinline__ f32x2 pkmul(f32x2 a, f32x2 b) {
  f32x2 d;
  asm("v_pk_mul_f32 %0, %1, %2" : "=v"(d) : "v"(a), "v"(b));
  return d;
}
// 1-inst clamps (med3 with inline consts)
static __device__ __forceinline__ float clamp2f(float x) {
  float d; asm("v_med3_f32 %0, %1, -2.0, 2.0" : "=v"(d) : "v"(x)); return d;
}
static __device__ __forceinline__ float clamp4f(float x) {
  float d; asm("v_med3_f32 %0, %1, -4.0, 4.0" : "=v"(d) : "v"(x)); return d;
}

// r8 structure (165us verified): 256 blocks x 512 thr, 8 waves, NB=16,
// one RAW barrier/step. r12 changes ONLY the epilogue engine:
//  - packed-f32 polynomial gates (v_pk_fma_f32): ~164 -> ~92 VALU/lane/step
//  - global h stores pipelined one barrier late -> fill ds_read latency shadow
__global__ __launch_bounds__(512, 1)
void enc_kernel(const float* __restrict__ X, const float* __restrict__ yprev,
                const float* __restrict__ Wa,
                const float* __restrict__ Wih1, const float* __restrict__ Whh1,
                const float* __restrict__ bih1, const float* __restrict__ bhh1,
                const float* __restrict__ Wih2, const float* __restrict__ Whh2,
                const float* __restrict__ bih2, const float* __restrict__ bhh2,
                float* __restrict__ out)
{
  const int tid  = threadIdx.x;
  const int wv   = tid >> 6;
  const int lane = tid & 63;
  const int l15  = lane & 15;
  const int lg   = lane >> 4;            // k-group 0..3
  const int lstm  = blockIdx.x >> 7;
  const int btile = blockIdx.x & 127;

  const float* Wih = lstm ? Wih2 : Wih1;
  const float* Whh = lstm ? Whh2 : Whh1;
  const float* bih = lstm ? bih2 : bih1;
  const float* bhh = lstm ? bhh2 : bhh1;
  const int Kin = lstm ? 15 : 16;

  __shared__ __align__(16) unsigned short h_lds[2][NB * HDIM];
  __shared__ __align__(16) unsigned short xt_lds[2][NB * 40];

  // packed-poly coefficient pairs (hoisted; ~22 VGPR — free at 1 blk/CU)
  const f32x2 TA = {0.00282f, 0.00282f},     TB = {-0.0281139f, -0.0281139f};
  const f32x2 TC = {0.1176519f, 0.1176519f}, TD = {-0.3307639f, -0.3307639f};
  const f32x2 SA = {1.10156e-5f, 1.10156e-5f}, SB = {-4.3928e-4f, -4.3928e-4f};
  const f32x2 SC = {7.3532e-3f, 7.3532e-3f},   SD = {-0.08269098f, -0.08269098f};
  const f32x2 ONE2 = {1.0f, 1.0f}, QUART2 = {0.25f, 0.25f}, HALF2 = {0.5f, 0.5f};

  auto tanh2 = [&](f32x2 x) -> f32x2 {
    x[0] = clamp2f(x[0]); x[1] = clamp2f(x[1]);
    const f32x2 t = pkmul(x, x);
    f32x2 p = pkfma(t, TA, TB);
    p = pkfma(p, t, TC);
    p = pkfma(p, t, TD);
    p = pkfma(p, t, ONE2);
    return pkmul(x, p);
  };
  auto sigm2 = [&](f32x2 x) -> f32x2 {
    x[0] = clamp4f(x[0]); x[1] = clamp4f(x[1]);
    const f32x2 t = pkmul(x, x);
    f32x2 p = pkfma(t, SA, SB);
    p = pkfma(p, t, SC);
    p = pkfma(p, t, SD);
    p = pkfma(p, t, ONE2);
    return pkfma(pkmul(x, p), QUART2, HALF2);
  };

  // ---- time-invariant weight B-fragments in registers ----
  bfrag wb[4][4];
  bfrag wi[4];
  float bias[4];
  #pragma unroll
  for (int gt = 0; gt < 4; ++gt) {
    const int row = (gt * 8 + wv) * 16 + l15;
    const float* wr = Whh + row * HDIM;
    #pragma unroll
    for (int ks = 0; ks < 4; ++ks) {
      const int k0 = ks * 32 + lg * 8;
      bfrag v;
      #pragma unroll
      for (int e = 0; e < 8; ++e) v[e] = (short)f2bf(wr[k0 + e]);
      wb[gt][ks] = v;
    }
    bfrag v;
    #pragma unroll
    for (int e = 0; e < 8; ++e) {
      const int k = lg * 8 + e;
      v[e] = (k < Kin) ? (short)f2bf(Wih[row * Kin + k]) : (short)0;
    }
    wi[gt] = v;
    bias[gt] = bih[row] + bhh[row];
  }

  // ---- attention (r8-verified): h/c terms cancel; time-invariant ----
  float a_bk = 0.0f;
  const int bloc = (tid >> 4) & 15;
  const int kf   = tid & 15;
  const size_t bg = (size_t)btile * NB + bloc;
  if (tid < 256) {
    float s = -1e30f;
    if (kf < Kin) {
      s = 0.0f;
      const float* xrow = X + bg * TSTEPS * 15;
      const float* yrow = yprev + bg * TSTEPS;
      for (int t = 0; t < TSTEPS; ++t) {
        const float wa = Wa[256 + t];
        float feat;
        if (lstm == 0) feat = (kf < 15) ? xrow[t * 15 + kf] : yrow[t];
        else           feat = xrow[t * 15 + kf] * yrow[t];
        s += feat * wa;
      }
    }
    float mx = s;
    #pragma unroll
    for (int m = 1; m < 16; m <<= 1) mx = fmaxf(mx, __shfl_xor(mx, m));
    const float e = __expf(s - mx);
    float sum = e;
    #pragma unroll
    for (int m = 1; m < 16; m <<= 1) sum += __shfl_xor(sum, m);
    a_bk = e / sum;
  }

  // ---- zero LDS (incl. xt K-pad), then barrier BEFORE prologue staging ----
  for (int i = tid; i < 2 * NB * HDIM; i += 512) ((unsigned short*)h_lds)[i] = 0;
  for (int i = tid; i < 2 * NB * 40;   i += 512) ((unsigned short*)xt_lds)[i] = 0;
  __syncthreads();

  // ---- strength-reduced output/input pointers ----
  const size_t XT_TOTAL = (size_t)NBATCH * TSTEPS * 16;
  const int u = wv * 16 + l15;
  float* pH[4];
  #pragma unroll
  for (int r = 0; r < 4; ++r) {
    const int b = lg * 4 + r;
    const size_t bgr = (size_t)btile * NB + b;
    pH[r] = out + XT_TOTAL + bgr * (TSTEPS * 256) + (size_t)lstm * 128 + u;
  }
  float* pXT = out + bg * (TSTEPS * 16) + kf;
  const float* pX = X + bg * (TSTEPS * 15) + kf;
  const float* pY = yprev + bg * TSTEPS;

  // ---- prologue: stage xt(0), prefetch (xv,yv) for s=1 ----
  float xv = 0.f, yv = 0.f;
  if (tid < 256) {
    yv = pY[0];
    if (kf < 15) xv = pX[0];
    float feat;
    if (lstm == 0) feat = (kf < 15) ? xv : yv;
    else           feat = (kf < 15) ? xv * yv : 0.0f;
    const float xt = a_bk * feat;
    xt_lds[0][bloc * 40 + kf] = f2bf(xt);
    if (lstm == 0) pXT[0] = xt;
    yv = pY[1];
    if (kf < 15) xv = pX[15];
  }
  __syncthreads();

  f32x2 cr01 = {0.f, 0.f}, cr23 = {0.f, 0.f};   // packed c-state (rows r0,r1 / r2,r3)
  f32x2 hp01 = {0.f, 0.f}, hp23 = {0.f, 0.f};   // pipelined h(t-1) for global store

  #pragma unroll 2
  for (int t = 0; t < TSTEPS; ++t) {
    // ---- A-fragments: h(t-1) from buf (t+1)&1, xt(t) from buf t&1 ----
    bfrag ah[4], ax;
    #pragma unroll
    for (int ks = 0; ks < 4; ++ks) {
      const int idx = (l15 * HDIM + ks * 32 + lg * 8) ^ (l15 << 3);
      ah[ks] = *(const bfrag*)&h_lds[(t + 1) & 1][idx];
    }
    ax = *(const bfrag*)&xt_lds[t & 1][l15 * 40 + lg * 8];

    // ---- pipelined global h(t-1) stores: fill the ds_read latency shadow ----
    if (t) {
      *pH[0] = hp01[0];  pH[0] += 256;
      *pH[1] = hp01[1];  pH[1] += 256;
      *pH[2] = hp23[0];  pH[2] += 256;
      *pH[3] = hp23[1];  pH[3] += 256;
    }

    // ---- 20 MFMAs/wave ----
    f32x4 acc[4];
    #pragma unroll
    for (int gt = 0; gt < 4; ++gt) {
      f32x4 a = {bias[gt], bias[gt], bias[gt], bias[gt]};
      #pragma unroll
      for (int ks = 0; ks < 4; ++ks)
        a = __builtin_amdgcn_mfma_f32_16x16x32_bf16(ah[ks], wb[gt][ks], a, 0, 0, 0);
      a = __builtin_amdgcn_mfma_f32_16x16x32_bf16(ax, wi[gt], a, 0, 0, 0);
      acc[gt] = a;
    }

    // ---- packed epilogue: rows (0,1) and (2,3) as f32x2 pairs ----
    {
      const f32x2 i01 = sigm2(f32x2{acc[0][0], acc[0][1]});
      const f32x2 f01 = sigm2(f32x2{acc[1][0], acc[1][1]});
      const f32x2 g01 = tanh2(f32x2{acc[2][0], acc[2][1]});
      const f32x2 o01 = sigm2(f32x2{acc[3][0], acc[3][1]});
      cr01 = pkfma(f01, cr01, pkmul(i01, g01));
      const f32x2 h01 = pkmul(o01, tanh2(cr01));
      const f32x2 i23 = sigm2(f32x2{acc[0][2], acc[0][3]});
      const f32x2 f23 = sigm2(f32x2{acc[1][2], acc[1][3]});
      const f32x2 g23 = tanh2(f32x2{acc[2][2], acc[2][3]});
      const f32x2 o23 = sigm2(f32x2{acc[3][2], acc[3][3]});
      cr23 = pkfma(f23, cr23, pkmul(i23, g23));
      const f32x2 h23 = pkmul(o23, tanh2(cr23));

      const int b0 = lg * 4;
      h_lds[t & 1][((b0 + 0) * HDIM + u) ^ ((b0 + 0) << 3)] = f2bf_fast(h01[0]);
      h_lds[t & 1][((b0 + 1) * HDIM + u) ^ ((b0 + 1) << 3)] = f2bf_fast(h01[1]);
      h_lds[t & 1][((b0 + 2) * HDIM + u) ^ ((b0 + 2) << 3)] = f2bf_fast(h23[0]);
      h_lds[t & 1][((b0 + 3) * HDIM + u) ^ ((b0 + 3) << 3)] = f2bf_fast(h23[1]);
      hp01 = h01;  hp23 = h23;
    }

    // ---- stage xt(t+1) into buf (t+1)&1, prefetch s=t+2 ----
    if (tid < 256 && t < TSTEPS - 1) {
      float feat;
      if (lstm == 0) feat = (kf < 15) ? xv : yv;
      else           feat = (kf < 15) ? xv * yv : 0.0f;
      const float xt = a_bk * feat;
      xt_lds[(t + 1) & 1][bloc * 40 + kf] = f2bf_fast(xt);
      if (lstm == 0) pXT[(size_t)(t + 1) * 16] = xt;
      if (t < TSTEPS - 2) {
        yv = pY[t + 2];
        if (kf < 15) xv = pX[(size_t)(t + 2) * 15];
      }
    }

    // ---- RAW barrier: LDS-only ordering; vmcnt free-running ----
    asm volatile("s_waitcnt lgkmcnt(0)" ::: "memory");
    __builtin_amdgcn_s_barrier();
    __builtin_amdgcn_sched_barrier(0);
  }
  // drain pipelined stores for t = TSTEPS-1
  *pH[0] = hp01[0];
  *pH[1] = hp01[1];
  *pH[2] = hp23[0];
  *pH[3] = hp23[1];
}

extern "C" void kernel_launch(void* const* d_in, const int* in_sizes, int n_in,
                              void* d_out, int out_size, void* d_ws, size_t ws_size,
                              hipStream_t stream) {
  const float* X    = (const float*)d_in[0];
  const float* yp   = (const float*)d_in[1];
  const float* Wa   = (const float*)d_in[2];
  // d_in[3] = ba: shift-invariant under softmax, unused
  const float* Wih1 = (const float*)d_in[4];
  const float* Whh1 = (const float*)d_in[5];
  const float* bih1 = (const float*)d_in[6];
  const float* bhh1 = (const float*)d_in[7];
  const float* Wih2 = (const float*)d_in[8];
  const float* Whh2 = (const float*)d_in[9];
  const float* bih2 = (const float*)d_in[10];
  const float* bhh2 = (const float*)d_in[11];
  float* out = (float*)d_out;

  enc_kernel<<<dim3(256), dim3(512), 0, stream>>>(
      X, yp, Wa, Wih1, Whh1, bih1, bhh1, Wih2, Whh2, bih2, bhh2, out);
}